// Round 17
// baseline (449.332 us; speedup 1.0000x reference)
//
#include <hip/hip_runtime.h>
#include <hip/hip_bf16.h>
#include <hip/hip_fp16.h>
#include <stdint.h>

#define DD 128
#define HH 8
#define DKK 16

#define CSHIFT 9                 // 512 nodes per coarse bucket
#define CNODES (1 << CSHIFT)
#define NCMAX 256                // >= ceil(100000/512)=196
#define ECAP 18432               // region cap: mean 16384 + 16 sigma
#define SC_EPT 16                // edges per thread in scatter

typedef __attribute__((ext_vector_type(8))) short bf16x8;
typedef __attribute__((ext_vector_type(4))) float f32x4;
typedef _Float16 h2 __attribute__((ext_vector_type(2)));
union u32h2 { unsigned u; h2 h; };

__device__ __forceinline__ float bflo2f(unsigned u) {
  union { unsigned i; float f; } c; c.i = u << 16; return c.f;
}
__device__ __forceinline__ unsigned short f2bf(float f) {
  __hip_bfloat16 b = __float2bfloat16(f);
  return *reinterpret_cast<unsigned short*>(&b);
}

// ---------------------------------------------------------------------------
// prep_weights: fold per-head relation transforms + mu scale into bf16
// WcatT[o][f] (o: 0-127 Q*mu/4, 128-255 K_eff, 256-383 V_eff) + bias.
// ---------------------------------------------------------------------------
__global__ __launch_bounds__(256) void prep_weights(
    const float* __restrict__ Wq, const float* __restrict__ bq,
    const float* __restrict__ Wk, const float* __restrict__ bk,
    const float* __restrict__ Wv, const float* __restrict__ bv,
    const float* __restrict__ w_att, const float* __restrict__ w_msg,
    const float* __restrict__ mu,
    unsigned short* __restrict__ WcatT, float* __restrict__ bcat) {
  int gid = blockIdx.x * 256 + threadIdx.x;  // 0 .. 128*384-1
  if (gid >= DD * 384) return;
  int f = gid / 384;
  int o = gid % 384;
  float scale = mu[0] * 0.25f;  // mu / sqrt(dk), dk=16
  float w;
  if (o < 128) {
    w = Wq[o * DD + f] * scale;
  } else if (o < 256) {
    int c = o - 128, h = c >> 4, j = c & 15;
    float s = 0.f;
#pragma unroll
    for (int i = 0; i < 16; ++i)
      s += Wk[(h * 16 + i) * DD + f] * w_att[h * 256 + i * 16 + j];
    w = s;
  } else {
    int c = o - 256, h = c >> 4, j = c & 15;
    float s = 0.f;
#pragma unroll
    for (int i = 0; i < 16; ++i)
      s += Wv[(h * 16 + i) * DD + f] * w_msg[h * 256 + i * 16 + j];
    w = s;
  }
  WcatT[(size_t)o * DD + f] = f2bf(w);
  if (f == 0) {
    float b;
    if (o < 128) {
      b = bq[o] * scale;
    } else if (o < 256) {
      int c = o - 128, h = c >> 4, j = c & 15;
      float s = 0.f;
#pragma unroll
      for (int i = 0; i < 16; ++i)
        s += bk[h * 16 + i] * w_att[h * 256 + i * 16 + j];
      b = s;
    } else {
      int c = o - 256, h = c >> 4, j = c & 15;
      float s = 0.f;
#pragma unroll
      for (int i = 0; i < 16; ++i)
        s += bv[h * 16 + i] * w_msg[h * 256 + i * 16 + j];
      b = s;
    }
    bcat[o] = b;
  }
}

// ---------------------------------------------------------------------------
// M2: fused proj_gemm (even blocks) || coarse scatter (odd blocks).
// proj: MFMA, no LDS, 128 rows/block, 2 A-frags/wave. Q->f16; KVrow layout
// now 512B/node, head h at h*64: [K-f16 32B][V-u8 16B][sV-bf16 2B][pad].
// Every head row is one 64B line; scale embedded (no separate S array).
// scatter: LDS counting over coarse buckets + cursor-append into FIXED
// regions ebuf[c*ECAP ..].
// ---------------------------------------------------------------------------
__global__ __launch_bounds__(256) void proj_and_scatter(
    const float* __restrict__ feat, const unsigned short* __restrict__ WcatT,
    const float* __restrict__ bcat, __half* __restrict__ Qh,
    unsigned char* __restrict__ KVrow, int N,
    const int* __restrict__ src, const int* __restrict__ dst,
    int* __restrict__ ccursor, unsigned* __restrict__ ebuf, int E, int NC,
    int PB, int SB) {
  __shared__ int hst[NCMAX];
  __shared__ int cur[NCMAX];
  int sub = blockIdx.x >> 1;
  int tid = threadIdx.x;

  if ((blockIdx.x & 1) == 0) {
    if (sub >= PB) return;
    int row0 = sub * 128;
    int wave = tid >> 6, lane = tid & 63;
    int lrow = lane & 15, lk = lane >> 4;

    bf16x8 a0[4], a1[4];
#pragma unroll
    for (int fr = 0; fr < 2; ++fr) {
      int arow = row0 + wave * 32 + fr * 16 + lrow;
      const float* ap = feat + (size_t)(arow < N ? arow : 0) * DD;
#pragma unroll
      for (int ks = 0; ks < 4; ++ks) {
        float4 v0 = *(const float4*)(ap + ks * 32 + lk * 8);
        float4 v1 = *(const float4*)(ap + ks * 32 + lk * 8 + 4);
        union { bf16x8 v; unsigned short s[8]; } u;
        u.s[0] = f2bf(v0.x); u.s[1] = f2bf(v0.y);
        u.s[2] = f2bf(v0.z); u.s[3] = f2bf(v0.w);
        u.s[4] = f2bf(v1.x); u.s[5] = f2bf(v1.y);
        u.s[6] = f2bf(v1.z); u.s[7] = f2bf(v1.w);
        if (fr == 0) a0[ks] = u.v; else a1[ks] = u.v;
      }
    }

#pragma unroll
    for (int nf = 0; nf < 24; ++nf) {
      f32x4 acc0 = (f32x4){0.f, 0.f, 0.f, 0.f};
      f32x4 acc1 = (f32x4){0.f, 0.f, 0.f, 0.f};
#pragma unroll
      for (int ks = 0; ks < 4; ++ks) {
        bf16x8 b = *(const bf16x8*)(WcatT + (size_t)(nf * 16 + lrow) * DD +
                                    ks * 32 + lk * 8);
        acc0 = __builtin_amdgcn_mfma_f32_16x16x32_bf16(a0[ks], b, acc0, 0, 0, 0);
        acc1 = __builtin_amdgcn_mfma_f32_16x16x32_bf16(a1[ks], b, acc1, 0, 0, 0);
      }
      int col = nf * 16 + lrow;
      float bias = bcat[col];
#pragma unroll
      for (int fr = 0; fr < 2; ++fr) {
        f32x4 acc = fr == 0 ? acc0 : acc1;
        int outrow = row0 + wave * 32 + fr * 16 + lk * 4;
#pragma unroll
        for (int r = 0; r < 4; ++r) {
          int grow = outrow + r;
          float c = acc[r] + bias;
          if (nf < 8) {
            if (grow < N) Qh[(size_t)grow * DD + col] = __float2half(c);
          } else if (nf < 16) {
            int h = nf - 8;
            if (grow < N)
              *(__half*)(KVrow + (size_t)grow * 512 + h * 64 + lrow * 2) =
                  __float2half(c);
          } else {
            int h = nf - 16;
            float av = fabsf(c);
            av = fmaxf(av, __shfl_xor(av, 1));
            av = fmaxf(av, __shfl_xor(av, 2));
            av = fmaxf(av, __shfl_xor(av, 4));
            av = fmaxf(av, __shfl_xor(av, 8));
            float iv = (av > 0.f) ? 127.f / av : 0.f;
            int qv = (int)rintf(c * iv) + 128;
            qv = qv < 0 ? 0 : (qv > 255 ? 255 : qv);
            unsigned tmp = (unsigned)qv << ((lrow & 3) * 8);
            tmp |= __shfl_xor(tmp, 1);
            tmp |= __shfl_xor(tmp, 2);
            if ((lrow & 3) == 0 && grow < N)
              *(unsigned*)(KVrow + (size_t)grow * 512 + h * 64 + 32 +
                           (lrow >> 2) * 4) = tmp;
            if (lrow == 0 && grow < N)
              *(unsigned short*)(KVrow + (size_t)grow * 512 + h * 64 + 48) =
                  f2bf(av / 127.f);
          }
        }
      }
    }
  } else {
    if (sub >= SB) return;
    int base0 = sub * (256 * SC_EPT);
    for (int i = tid; i < NC; i += 256) hst[i] = 0;
    __syncthreads();
    int myd[SC_EPT], mys[SC_EPT];
#pragma unroll
    for (int i = 0; i < SC_EPT; ++i) {
      int e = base0 + i * 256 + tid;
      if (e < E) {
        myd[i] = dst[e];
        mys[i] = src[e];
        atomicAdd(&hst[myd[i] >> CSHIFT], 1);
      } else {
        myd[i] = -1;
      }
    }
    __syncthreads();
    for (int i = tid; i < NC; i += 256)
      cur[i] = hst[i] ? atomicAdd(&ccursor[i], hst[i]) : 0;
    __syncthreads();
#pragma unroll
    for (int i = 0; i < SC_EPT; ++i) {
      if (myd[i] >= 0) {
        int b = myd[i] >> CSHIFT;
        int p = atomicAdd(&cur[b], 1);
        ebuf[(size_t)b * ECAP + p] =
            ((unsigned)(myd[i] & (CNODES - 1)) << 17) | (unsigned)mys[i];
      }
    }
  }
}

// ---------------------------------------------------------------------------
// Coarse region -> per-node CSR (verified form, fixed-region input).
// One block (512 threads) per coarse bucket: LDS per-node hist +
// Hillis-Steele scan, write rowptr/deg, LDS-cursor scatter of src ids.
// ---------------------------------------------------------------------------
__global__ __launch_bounds__(512) void coarse_to_csr(
    const unsigned* __restrict__ ebuf, const int* __restrict__ ccursor,
    int* __restrict__ rowptr, int* __restrict__ deg, int* __restrict__ esrc,
    int N) {
  __shared__ int h[CNODES];
  __shared__ int sc[CNODES];
  __shared__ int cur[CNODES];
  int c = blockIdx.x;
  int tid = threadIdx.x;
  size_t start = (size_t)c * ECAP;
  int cnt = ccursor[c];
  h[tid] = 0;
  __syncthreads();
  for (int i = tid; i < cnt; i += 512)
    atomicAdd(&h[ebuf[start + i] >> 17], 1);
  __syncthreads();
  sc[tid] = h[tid];
  __syncthreads();
  for (int off = 1; off < CNODES; off <<= 1) {
    int t = (tid >= off) ? sc[tid - off] : 0;
    __syncthreads();
    sc[tid] += t;
    __syncthreads();
  }
  {
    int excl = sc[tid] - h[tid];
    int node = c * CNODES + tid;
    if (node < N) {
      rowptr[node] = (int)(start + excl);
      deg[node] = h[tid];
    }
    cur[tid] = excl;
  }
  __syncthreads();
  for (int i = tid; i < cnt; i += 512) {
    unsigned u = ebuf[start + i];
    int p = atomicAdd(&cur[u >> 17], 1);
    esrc[start + p] = (int)(u & 0x1FFFFu);
  }
}

// ---------------------------------------------------------------------------
// Fused node-centric attention (verified form), 8 edges/wave, one head per
// lane. Per edge-head lane: ONE 64B-aligned line [K-f16 32B][V-u8 16B]
// [sV 2B][pad]. fdot2 K-dot; biased-u8 V with evsum correction. Q f16.
// NaN-proofed.
// ---------------------------------------------------------------------------
__global__ __launch_bounds__(256) void node_aggregate(
    const int* __restrict__ esrc, const int* __restrict__ rowptr,
    const int* __restrict__ deg, const __half* __restrict__ Qh,
    const unsigned char* __restrict__ KVrow,
    float* __restrict__ out, int N) {
  int n = blockIdx.x * 4 + (threadIdx.x >> 6);
  if (n >= N) return;
  int lane = threadIdx.x & 63;
  int hd = lane & 7;
  int p = lane >> 3;

  h2 qh[8];
  {
    const unsigned* qp = (const unsigned*)Qh + (size_t)n * 64 + hd * 8;
#pragma unroll
    for (int w = 0; w < 8; ++w) {
      u32h2 t; t.u = qp[w]; qh[w] = t.h;
    }
  }
  int row = rowptr[n];
  int dg = deg[n];

  float acc[16];
#pragma unroll
  for (int j = 0; j < 16; ++j) acc[j] = 0.f;
  float den = 0.f, evsum = 0.f;

  for (int base = 0; base < dg; base += 64) {
    int myid = (base + lane < dg) ? esrc[row + base + lane] : 0;
    int cnt = min(64, dg - base);
    int iters = (cnt + 7) >> 3;
#pragma unroll 4
    for (int i = 0; i < iters; ++i) {
      int slot = i * 8 + p;
      int s = __shfl(myid, slot);
      float m = (base + slot < dg) ? 1.f : 0.f;
      const unsigned char* rp = KVrow + (size_t)s * 512 + hd * 64;
      uint4 k0 = *(const uint4*)rp;
      uint4 k1 = *(const uint4*)(rp + 16);
      uint4 vq = *(const uint4*)(rp + 32);
      float sV = bflo2f((unsigned)*(const unsigned short*)(rp + 48));
      u32h2 c0, c1, c2, c3;
      c0.u = k0.x; c1.u = k0.y; c2.u = k0.z; c3.u = k0.w;
      float dA = __builtin_amdgcn_fdot2(qh[0], c0.h, 0.f, false);
      float dB = __builtin_amdgcn_fdot2(qh[1], c1.h, 0.f, false);
      dA = __builtin_amdgcn_fdot2(qh[2], c2.h, dA, false);
      dB = __builtin_amdgcn_fdot2(qh[3], c3.h, dB, false);
      c0.u = k1.x; c1.u = k1.y; c2.u = k1.z; c3.u = k1.w;
      dA = __builtin_amdgcn_fdot2(qh[4], c0.h, dA, false);
      dB = __builtin_amdgcn_fdot2(qh[5], c1.h, dB, false);
      dA = __builtin_amdgcn_fdot2(qh[6], c2.h, dA, false);
      dB = __builtin_amdgcn_fdot2(qh[7], c3.h, dB, false);
      float dot = dA + dB;
      float ex = m * __expf(fminf(dot, 80.f));
      den += ex;
      float evs = ex * sV;
      evsum += evs;
      acc[0] = fmaf(evs, (float)(vq.x & 255), acc[0]);
      acc[1] = fmaf(evs, (float)((vq.x >> 8) & 255), acc[1]);
      acc[2] = fmaf(evs, (float)((vq.x >> 16) & 255), acc[2]);
      acc[3] = fmaf(evs, (float)(vq.x >> 24), acc[3]);
      acc[4] = fmaf(evs, (float)(vq.y & 255), acc[4]);
      acc[5] = fmaf(evs, (float)((vq.y >> 8) & 255), acc[5]);
      acc[6] = fmaf(evs, (float)((vq.y >> 16) & 255), acc[6]);
      acc[7] = fmaf(evs, (float)(vq.y >> 24), acc[7]);
      acc[8] = fmaf(evs, (float)(vq.z & 255), acc[8]);
      acc[9] = fmaf(evs, (float)((vq.z >> 8) & 255), acc[9]);
      acc[10] = fmaf(evs, (float)((vq.z >> 16) & 255), acc[10]);
      acc[11] = fmaf(evs, (float)(vq.z >> 24), acc[11]);
      acc[12] = fmaf(evs, (float)(vq.w & 255), acc[12]);
      acc[13] = fmaf(evs, (float)((vq.w >> 8) & 255), acc[13]);
      acc[14] = fmaf(evs, (float)((vq.w >> 16) & 255), acc[14]);
      acc[15] = fmaf(evs, (float)(vq.w >> 24), acc[15]);
    }
  }

#pragma unroll
  for (int j = 0; j < 16; ++j) {
    acc[j] += __shfl_xor(acc[j], 8);
    acc[j] += __shfl_xor(acc[j], 16);
    acc[j] += __shfl_xor(acc[j], 32);
  }
  den += __shfl_xor(den, 8);
  den += __shfl_xor(den, 16);
  den += __shfl_xor(den, 32);
  evsum += __shfl_xor(evsum, 8);
  evsum += __shfl_xor(evsum, 16);
  evsum += __shfl_xor(evsum, 32);

  if (p == 0) {
    float inv = (dg > 0 && den > 0.f) ? 1.0f / den : 0.f;
    float corr = 128.f * evsum;
#pragma unroll
    for (int i = 0; i < 4; ++i) {
      float4 o = make_float4((acc[i * 4 + 0] - corr) * inv,
                             (acc[i * 4 + 1] - corr) * inv,
                             (acc[i * 4 + 2] - corr) * inv,
                             (acc[i * 4 + 3] - corr) * inv);
      *(float4*)(out + (size_t)n * DD + hd * DKK + i * 4) = o;
    }
  }
}

// ---------------------------------------------------------------------------
extern "C" void kernel_launch(void* const* d_in, const int* in_sizes, int n_in,
                              void* d_out, int out_size, void* d_ws,
                              size_t ws_size, hipStream_t stream) {
  const float* feat = (const float*)d_in[0];
  const float* Wk = (const float*)d_in[1];
  const float* bk = (const float*)d_in[2];
  const float* Wq = (const float*)d_in[3];
  const float* bq = (const float*)d_in[4];
  const float* Wv = (const float*)d_in[5];
  const float* bv = (const float*)d_in[6];
  const float* w_att = (const float*)d_in[7];
  const float* w_msg = (const float*)d_in[8];
  const float* mu = (const float*)d_in[9];
  const int* src = (const int*)d_in[10];
  const int* dst = (const int*)d_in[11];

  int N = in_sizes[0] / DD;
  int E = in_sizes[10];
  int NC = (N + CNODES - 1) >> CSHIFT;

  char* ws = (char*)d_ws;
  unsigned short* WcatT = (unsigned short*)ws; ws += (size_t)DD * 384 * 2;
  float* bcat = (float*)ws; ws += 384 * 4;
  ws = (char*)(((uintptr_t)ws + 255) & ~(uintptr_t)255);
  __half* Qh = (__half*)ws; ws += (size_t)N * DD * 2;
  ws = (char*)(((uintptr_t)ws + 255) & ~(uintptr_t)255);
  unsigned char* KVrow = (unsigned char*)ws; ws += (size_t)N * 512;
  ws = (char*)(((uintptr_t)ws + 255) & ~(uintptr_t)255);
  int* ccursor = (int*)ws; ws += NCMAX * 4;
  int* rowptr = (int*)ws; ws += (size_t)N * 4;
  int* deg = (int*)ws; ws += (size_t)N * 4;
  ws = (char*)(((uintptr_t)ws + 255) & ~(uintptr_t)255);
  unsigned* ebuf = (unsigned*)ws; ws += (size_t)NC * ECAP * 4;
  int* esrc = (int*)ws; ws += (size_t)NC * ECAP * 4;

  hipMemsetAsync(ccursor, 0, NCMAX * 4, stream);

  prep_weights<<<192, 256, 0, stream>>>(Wq, bq, Wk, bk, Wv, bv, w_att, w_msg,
                                        mu, WcatT, bcat);

  int PB = (N + 127) / 128;
  int SB = (E + 256 * SC_EPT - 1) / (256 * SC_EPT);
  int MB = PB > SB ? PB : SB;
  proj_and_scatter<<<2 * MB, 256, 0, stream>>>(
      feat, WcatT, bcat, Qh, KVrow, N, src, dst, ccursor, ebuf, E, NC, PB,
      SB);

  coarse_to_csr<<<NC, 512, 0, stream>>>(ebuf, ccursor, rowptr, deg, esrc, N);

  node_aggregate<<<(N + 3) / 4, 256, 0, stream>>>(esrc, rowptr, deg, Qh,
                                                  KVrow, (float*)d_out, N);
}

// Round 18
// 353.446 us; speedup vs baseline: 1.2713x; 1.2713x over previous
//
#include <hip/hip_runtime.h>
#include <hip/hip_bf16.h>
#include <hip/hip_fp16.h>
#include <stdint.h>

#define DD 128
#define HH 8
#define DKK 16

#define CSHIFT 9                 // 512 nodes per coarse bucket
#define CNODES (1 << CSHIFT)
#define NCMAX 256                // >= ceil(100000/512)=196
#define ECAP 18432               // region cap: mean 16384 + 16 sigma
#define SC_EPT 16                // edges per thread in scatter

typedef __attribute__((ext_vector_type(8))) short bf16x8;
typedef __attribute__((ext_vector_type(4))) float f32x4;
typedef _Float16 h2 __attribute__((ext_vector_type(2)));
union u32h2 { unsigned u; h2 h; };

__device__ __forceinline__ float bflo2f(unsigned u) {
  union { unsigned i; float f; } c; c.i = u << 16; return c.f;
}
__device__ __forceinline__ unsigned short f2bf(float f) {
  __hip_bfloat16 b = __float2bfloat16(f);
  return *reinterpret_cast<unsigned short*>(&b);
}

// ---------------------------------------------------------------------------
// prep_weights: fold per-head relation transforms + mu scale into bf16
// WcatT[o][f] (o: 0-127 Q*mu/4, 128-255 K_eff, 256-383 V_eff) + bias.
// Block 0 also zeroes ccursor (folds the memset dispatch).
// ---------------------------------------------------------------------------
__global__ __launch_bounds__(256) void prep_weights(
    const float* __restrict__ Wq, const float* __restrict__ bq,
    const float* __restrict__ Wk, const float* __restrict__ bk,
    const float* __restrict__ Wv, const float* __restrict__ bv,
    const float* __restrict__ w_att, const float* __restrict__ w_msg,
    const float* __restrict__ mu,
    unsigned short* __restrict__ WcatT, float* __restrict__ bcat,
    int* __restrict__ ccursor) {
  if (blockIdx.x == 0 && threadIdx.x < NCMAX) ccursor[threadIdx.x] = 0;
  int gid = blockIdx.x * 256 + threadIdx.x;  // 0 .. 128*384-1
  if (gid >= DD * 384) return;
  int f = gid / 384;
  int o = gid % 384;
  float scale = mu[0] * 0.25f;  // mu / sqrt(dk), dk=16
  float w;
  if (o < 128) {
    w = Wq[o * DD + f] * scale;
  } else if (o < 256) {
    int c = o - 128, h = c >> 4, j = c & 15;
    float s = 0.f;
#pragma unroll
    for (int i = 0; i < 16; ++i)
      s += Wk[(h * 16 + i) * DD + f] * w_att[h * 256 + i * 16 + j];
    w = s;
  } else {
    int c = o - 256, h = c >> 4, j = c & 15;
    float s = 0.f;
#pragma unroll
    for (int i = 0; i < 16; ++i)
      s += Wv[(h * 16 + i) * DD + f] * w_msg[h * 256 + i * 16 + j];
    w = s;
  }
  WcatT[(size_t)o * DD + f] = f2bf(w);
  if (f == 0) {
    float b;
    if (o < 128) {
      b = bq[o] * scale;
    } else if (o < 256) {
      int c = o - 128, h = c >> 4, j = c & 15;
      float s = 0.f;
#pragma unroll
      for (int i = 0; i < 16; ++i)
        s += bk[h * 16 + i] * w_att[h * 256 + i * 16 + j];
      b = s;
    } else {
      int c = o - 256, h = c >> 4, j = c & 15;
      float s = 0.f;
#pragma unroll
      for (int i = 0; i < 16; ++i)
        s += bv[h * 16 + i] * w_msg[h * 256 + i * 16 + j];
      b = s;
    }
    bcat[o] = b;
  }
}

// ---------------------------------------------------------------------------
// M2: fused proj_gemm (even blocks) || coarse scatter (odd blocks).
// proj: MFMA, no LDS, 128 rows/block, 2 A-frags/wave. Q->f16; K->f16 into
// KVrow [node][h*48: K-f16 32B | V-u8 16B] (384B = exactly 3 L2 lines);
// V quantized in-epilogue; sV scales in separate L2-hot S array.
// scatter: LDS counting over coarse buckets + cursor-append into FIXED
// regions ebuf[c*ECAP ..].
// ---------------------------------------------------------------------------
__global__ __launch_bounds__(256) void proj_and_scatter(
    const float* __restrict__ feat, const unsigned short* __restrict__ WcatT,
    const float* __restrict__ bcat, __half* __restrict__ Qh,
    unsigned char* __restrict__ KVrow, unsigned short* __restrict__ S, int N,
    const int* __restrict__ src, const int* __restrict__ dst,
    int* __restrict__ ccursor, unsigned* __restrict__ ebuf, int E, int NC,
    int PB, int SB) {
  __shared__ int hst[NCMAX];
  __shared__ int cur[NCMAX];
  int sub = blockIdx.x >> 1;
  int tid = threadIdx.x;

  if ((blockIdx.x & 1) == 0) {
    if (sub >= PB) return;
    int row0 = sub * 128;
    int wave = tid >> 6, lane = tid & 63;
    int lrow = lane & 15, lk = lane >> 4;

    bf16x8 a0[4], a1[4];
#pragma unroll
    for (int fr = 0; fr < 2; ++fr) {
      int arow = row0 + wave * 32 + fr * 16 + lrow;
      const float* ap = feat + (size_t)(arow < N ? arow : 0) * DD;
#pragma unroll
      for (int ks = 0; ks < 4; ++ks) {
        float4 v0 = *(const float4*)(ap + ks * 32 + lk * 8);
        float4 v1 = *(const float4*)(ap + ks * 32 + lk * 8 + 4);
        union { bf16x8 v; unsigned short s[8]; } u;
        u.s[0] = f2bf(v0.x); u.s[1] = f2bf(v0.y);
        u.s[2] = f2bf(v0.z); u.s[3] = f2bf(v0.w);
        u.s[4] = f2bf(v1.x); u.s[5] = f2bf(v1.y);
        u.s[6] = f2bf(v1.z); u.s[7] = f2bf(v1.w);
        if (fr == 0) a0[ks] = u.v; else a1[ks] = u.v;
      }
    }

#pragma unroll
    for (int nf = 0; nf < 24; ++nf) {
      f32x4 acc0 = (f32x4){0.f, 0.f, 0.f, 0.f};
      f32x4 acc1 = (f32x4){0.f, 0.f, 0.f, 0.f};
#pragma unroll
      for (int ks = 0; ks < 4; ++ks) {
        bf16x8 b = *(const bf16x8*)(WcatT + (size_t)(nf * 16 + lrow) * DD +
                                    ks * 32 + lk * 8);
        acc0 = __builtin_amdgcn_mfma_f32_16x16x32_bf16(a0[ks], b, acc0, 0, 0, 0);
        acc1 = __builtin_amdgcn_mfma_f32_16x16x32_bf16(a1[ks], b, acc1, 0, 0, 0);
      }
      int col = nf * 16 + lrow;
      float bias = bcat[col];
#pragma unroll
      for (int fr = 0; fr < 2; ++fr) {
        f32x4 acc = fr == 0 ? acc0 : acc1;
        int outrow = row0 + wave * 32 + fr * 16 + lk * 4;
#pragma unroll
        for (int r = 0; r < 4; ++r) {
          int grow = outrow + r;
          float c = acc[r] + bias;
          if (nf < 8) {
            if (grow < N) Qh[(size_t)grow * DD + col] = __float2half(c);
          } else if (nf < 16) {
            int h = nf - 8;
            if (grow < N)
              *(__half*)(KVrow + (size_t)grow * 384 + h * 48 + lrow * 2) =
                  __float2half(c);
          } else {
            int h = nf - 16;
            float av = fabsf(c);
            av = fmaxf(av, __shfl_xor(av, 1));
            av = fmaxf(av, __shfl_xor(av, 2));
            av = fmaxf(av, __shfl_xor(av, 4));
            av = fmaxf(av, __shfl_xor(av, 8));
            float iv = (av > 0.f) ? 127.f / av : 0.f;
            int qv = (int)rintf(c * iv) + 128;
            qv = qv < 0 ? 0 : (qv > 255 ? 255 : qv);
            unsigned tmp = (unsigned)qv << ((lrow & 3) * 8);
            tmp |= __shfl_xor(tmp, 1);
            tmp |= __shfl_xor(tmp, 2);
            if ((lrow & 3) == 0 && grow < N)
              *(unsigned*)(KVrow + (size_t)grow * 384 + h * 48 + 32 +
                           (lrow >> 2) * 4) = tmp;
            if (lrow == 0 && grow < N)
              S[(size_t)grow * 8 + h] = f2bf(av / 127.f);
          }
        }
      }
    }
  } else {
    if (sub >= SB) return;
    int base0 = sub * (256 * SC_EPT);
    for (int i = tid; i < NC; i += 256) hst[i] = 0;
    __syncthreads();
    int myd[SC_EPT], mys[SC_EPT];
#pragma unroll
    for (int i = 0; i < SC_EPT; ++i) {
      int e = base0 + i * 256 + tid;
      if (e < E) {
        myd[i] = dst[e];
        mys[i] = src[e];
        atomicAdd(&hst[myd[i] >> CSHIFT], 1);
      } else {
        myd[i] = -1;
      }
    }
    __syncthreads();
    for (int i = tid; i < NC; i += 256)
      cur[i] = hst[i] ? atomicAdd(&ccursor[i], hst[i]) : 0;
    __syncthreads();
#pragma unroll
    for (int i = 0; i < SC_EPT; ++i) {
      if (myd[i] >= 0) {
        int b = myd[i] >> CSHIFT;
        int p = atomicAdd(&cur[b], 1);
        ebuf[(size_t)b * ECAP + p] =
            ((unsigned)(myd[i] & (CNODES - 1)) << 17) | (unsigned)mys[i];
      }
    }
  }
}

// ---------------------------------------------------------------------------
// Coarse region -> per-node CSR (verified form, fixed-region input).
// One block (512 threads) per coarse bucket: LDS per-node hist +
// Hillis-Steele scan, write rowptr/deg, LDS-cursor scatter of src ids.
// ---------------------------------------------------------------------------
__global__ __launch_bounds__(512) void coarse_to_csr(
    const unsigned* __restrict__ ebuf, const int* __restrict__ ccursor,
    int* __restrict__ rowptr, int* __restrict__ deg, int* __restrict__ esrc,
    int N) {
  __shared__ int h[CNODES];
  __shared__ int sc[CNODES];
  __shared__ int cur[CNODES];
  int c = blockIdx.x;
  int tid = threadIdx.x;
  size_t start = (size_t)c * ECAP;
  int cnt = ccursor[c];
  h[tid] = 0;
  __syncthreads();
  for (int i = tid; i < cnt; i += 512)
    atomicAdd(&h[ebuf[start + i] >> 17], 1);
  __syncthreads();
  sc[tid] = h[tid];
  __syncthreads();
  for (int off = 1; off < CNODES; off <<= 1) {
    int t = (tid >= off) ? sc[tid - off] : 0;
    __syncthreads();
    sc[tid] += t;
    __syncthreads();
  }
  {
    int excl = sc[tid] - h[tid];
    int node = c * CNODES + tid;
    if (node < N) {
      rowptr[node] = (int)(start + excl);
      deg[node] = h[tid];
    }
    cur[tid] = excl;
  }
  __syncthreads();
  for (int i = tid; i < cnt; i += 512) {
    unsigned u = ebuf[start + i];
    int p = atomicAdd(&cur[u >> 17], 1);
    esrc[start + p] = (int)(u & 0x1FFFFu);
  }
}

// ---------------------------------------------------------------------------
// Fused node-centric attention (r16-verified form), 8 edges/wave, one head
// per lane. Per edge-head lane: 48B row [K-f16 32B][V-u8 16B] + 2B sV.
// fdot2 K-dot (2 ILP chains); biased-u8 V with evsum correction. Q f16.
// NaN-proofed.
// ---------------------------------------------------------------------------
__global__ __launch_bounds__(256) void node_aggregate(
    const int* __restrict__ esrc, const int* __restrict__ rowptr,
    const int* __restrict__ deg, const __half* __restrict__ Qh,
    const unsigned char* __restrict__ KVrow,
    const unsigned short* __restrict__ S,
    float* __restrict__ out, int N) {
  int n = blockIdx.x * 4 + (threadIdx.x >> 6);
  if (n >= N) return;
  int lane = threadIdx.x & 63;
  int hd = lane & 7;
  int p = lane >> 3;

  h2 qh[8];
  {
    const unsigned* qp = (const unsigned*)Qh + (size_t)n * 64 + hd * 8;
#pragma unroll
    for (int w = 0; w < 8; ++w) {
      u32h2 t; t.u = qp[w]; qh[w] = t.h;
    }
  }
  int row = rowptr[n];
  int dg = deg[n];

  float acc[16];
#pragma unroll
  for (int j = 0; j < 16; ++j) acc[j] = 0.f;
  float den = 0.f, evsum = 0.f;

  for (int base = 0; base < dg; base += 64) {
    int myid = (base + lane < dg) ? esrc[row + base + lane] : 0;
    int cnt = min(64, dg - base);
    int iters = (cnt + 7) >> 3;
#pragma unroll 4
    for (int i = 0; i < iters; ++i) {
      int slot = i * 8 + p;
      int s = __shfl(myid, slot);
      float m = (base + slot < dg) ? 1.f : 0.f;
      const unsigned char* rp = KVrow + (size_t)s * 384 + hd * 48;
      uint4 k0 = *(const uint4*)rp;
      uint4 k1 = *(const uint4*)(rp + 16);
      uint4 vq = *(const uint4*)(rp + 32);
      float sV = bflo2f((unsigned)S[(size_t)s * 8 + hd]);
      u32h2 c0, c1, c2, c3;
      c0.u = k0.x; c1.u = k0.y; c2.u = k0.z; c3.u = k0.w;
      float dA = __builtin_amdgcn_fdot2(qh[0], c0.h, 0.f, false);
      float dB = __builtin_amdgcn_fdot2(qh[1], c1.h, 0.f, false);
      dA = __builtin_amdgcn_fdot2(qh[2], c2.h, dA, false);
      dB = __builtin_amdgcn_fdot2(qh[3], c3.h, dB, false);
      c0.u = k1.x; c1.u = k1.y; c2.u = k1.z; c3.u = k1.w;
      dA = __builtin_amdgcn_fdot2(qh[4], c0.h, dA, false);
      dB = __builtin_amdgcn_fdot2(qh[5], c1.h, dB, false);
      dA = __builtin_amdgcn_fdot2(qh[6], c2.h, dA, false);
      dB = __builtin_amdgcn_fdot2(qh[7], c3.h, dB, false);
      float dot = dA + dB;
      float ex = m * __expf(fminf(dot, 80.f));
      den += ex;
      float evs = ex * sV;
      evsum += evs;
      acc[0] = fmaf(evs, (float)(vq.x & 255), acc[0]);
      acc[1] = fmaf(evs, (float)((vq.x >> 8) & 255), acc[1]);
      acc[2] = fmaf(evs, (float)((vq.x >> 16) & 255), acc[2]);
      acc[3] = fmaf(evs, (float)(vq.x >> 24), acc[3]);
      acc[4] = fmaf(evs, (float)(vq.y & 255), acc[4]);
      acc[5] = fmaf(evs, (float)((vq.y >> 8) & 255), acc[5]);
      acc[6] = fmaf(evs, (float)((vq.y >> 16) & 255), acc[6]);
      acc[7] = fmaf(evs, (float)(vq.y >> 24), acc[7]);
      acc[8] = fmaf(evs, (float)(vq.z & 255), acc[8]);
      acc[9] = fmaf(evs, (float)((vq.z >> 8) & 255), acc[9]);
      acc[10] = fmaf(evs, (float)((vq.z >> 16) & 255), acc[10]);
      acc[11] = fmaf(evs, (float)(vq.z >> 24), acc[11]);
      acc[12] = fmaf(evs, (float)(vq.w & 255), acc[12]);
      acc[13] = fmaf(evs, (float)((vq.w >> 8) & 255), acc[13]);
      acc[14] = fmaf(evs, (float)((vq.w >> 16) & 255), acc[14]);
      acc[15] = fmaf(evs, (float)(vq.w >> 24), acc[15]);
    }
  }

#pragma unroll
  for (int j = 0; j < 16; ++j) {
    acc[j] += __shfl_xor(acc[j], 8);
    acc[j] += __shfl_xor(acc[j], 16);
    acc[j] += __shfl_xor(acc[j], 32);
  }
  den += __shfl_xor(den, 8);
  den += __shfl_xor(den, 16);
  den += __shfl_xor(den, 32);
  evsum += __shfl_xor(evsum, 8);
  evsum += __shfl_xor(evsum, 16);
  evsum += __shfl_xor(evsum, 32);

  if (p == 0) {
    float inv = (dg > 0 && den > 0.f) ? 1.0f / den : 0.f;
    float corr = 128.f * evsum;
#pragma unroll
    for (int i = 0; i < 4; ++i) {
      float4 o = make_float4((acc[i * 4 + 0] - corr) * inv,
                             (acc[i * 4 + 1] - corr) * inv,
                             (acc[i * 4 + 2] - corr) * inv,
                             (acc[i * 4 + 3] - corr) * inv);
      *(float4*)(out + (size_t)n * DD + hd * DKK + i * 4) = o;
    }
  }
}

// ---------------------------------------------------------------------------
extern "C" void kernel_launch(void* const* d_in, const int* in_sizes, int n_in,
                              void* d_out, int out_size, void* d_ws,
                              size_t ws_size, hipStream_t stream) {
  const float* feat = (const float*)d_in[0];
  const float* Wk = (const float*)d_in[1];
  const float* bk = (const float*)d_in[2];
  const float* Wq = (const float*)d_in[3];
  const float* bq = (const float*)d_in[4];
  const float* Wv = (const float*)d_in[5];
  const float* bv = (const float*)d_in[6];
  const float* w_att = (const float*)d_in[7];
  const float* w_msg = (const float*)d_in[8];
  const float* mu = (const float*)d_in[9];
  const int* src = (const int*)d_in[10];
  const int* dst = (const int*)d_in[11];

  int N = in_sizes[0] / DD;
  int E = in_sizes[10];
  int NC = (N + CNODES - 1) >> CSHIFT;

  char* ws = (char*)d_ws;
  unsigned short* WcatT = (unsigned short*)ws; ws += (size_t)DD * 384 * 2;
  float* bcat = (float*)ws; ws += 384 * 4;
  ws = (char*)(((uintptr_t)ws + 255) & ~(uintptr_t)255);
  __half* Qh = (__half*)ws; ws += (size_t)N * DD * 2;
  unsigned char* KVrow = (unsigned char*)ws; ws += (size_t)N * 384;
  ws = (char*)(((uintptr_t)ws + 255) & ~(uintptr_t)255);
  unsigned short* S = (unsigned short*)ws; ws += (size_t)N * HH * 2;
  ws = (char*)(((uintptr_t)ws + 255) & ~(uintptr_t)255);
  int* ccursor = (int*)ws; ws += NCMAX * 4;
  int* rowptr = (int*)ws; ws += (size_t)N * 4;
  int* deg = (int*)ws; ws += (size_t)N * 4;
  ws = (char*)(((uintptr_t)ws + 255) & ~(uintptr_t)255);
  unsigned* ebuf = (unsigned*)ws; ws += (size_t)NC * ECAP * 4;
  int* esrc = (int*)ws; ws += (size_t)NC * ECAP * 4;

  prep_weights<<<192, 256, 0, stream>>>(Wq, bq, Wk, bk, Wv, bv, w_att, w_msg,
                                        mu, WcatT, bcat, ccursor);

  int PB = (N + 127) / 128;
  int SB = (E + 256 * SC_EPT - 1) / (256 * SC_EPT);
  int MB = PB > SB ? PB : SB;
  proj_and_scatter<<<2 * MB, 256, 0, stream>>>(
      feat, WcatT, bcat, Qh, KVrow, S, N, src, dst, ccursor, ebuf, E, NC, PB,
      SB);

  coarse_to_csr<<<NC, 512, 0, stream>>>(ebuf, ccursor, rowptr, deg, esrc, N);

  node_aggregate<<<(N + 3) / 4, 256, 0, stream>>>(esrc, rowptr, deg, Qh,
                                                  KVrow, S, (float*)d_out, N);
}